// Round 12
// baseline (150.137 us; speedup 1.0000x reference)
//
#include <hip/hip_runtime.h>
#include <math.h>

#define NOSC 2048
#define NB 16
#define DT 0.1f
#define M_TOT (NB * NOSC)    // 32768
#define KTP 2056             // padded LDS K row

typedef __attribute__((ext_vector_type(8))) short bf16x8;
typedef __attribute__((ext_vector_type(4))) float f32x4;

__device__ __forceinline__ unsigned short f2bf(float x) {
    unsigned int u = __float_as_uint(x);
    u += 0x7FFFu + ((u >> 16) & 1u);          // round-to-nearest-even
    return (unsigned short)(u >> 16);
}
__device__ __forceinline__ float bf2f(unsigned short u) {
    return __uint_as_float(((unsigned int)u) << 16);
}

// ws layout: Kb[2048][2048] bf16 (8 MB) | RA [32][2048] bf16 | RB | accum[32] f32 | ticket int
// R rows 0..15 = sin(theta[b][:]), rows 16..31 = cos.
//
// Geometry: grid 256 = 128 i-tiles x 2 batch-halves -> 1 block/CU on ALL CUs.
// Block (it, bh): A-fragment rows 0..7 = sin of b=bh*8+r, rows 8..15 = cos of
// same batches  ->  D[16][16] holds both aS (rows 0..7) and aC (rows 8..15)
// for this block's 128 (b,i); theta update fully fused in-block.
// 16 waves, wave w = k-sixteenth (128 k = 4 MFMA of K=32), 8 frags upfront.
// MODE: 0 = FIRST (K convert + init from theta_in), 1 = MID, 2 = FINAL
// (atan2 wrap + fused coherence via atomics + last-block finalize).
template <int MODE>
__global__ __launch_bounds__(1024, 4) void step_kernel(
    const float* __restrict__ theta_in,
    const float* __restrict__ Kmat,
    unsigned short* __restrict__ Kb,
    const unsigned short* __restrict__ Rc,
    unsigned short* __restrict__ Rn,
    const float* __restrict__ omega,
    const float* __restrict__ kg,
    const float* __restrict__ mod,
    float* __restrict__ th,
    float* __restrict__ coh,
    float* __restrict__ accum,
    int* __restrict__ ticket)
{
    __shared__ float part[16][64][4];     // 16 KB
    __shared__ float coup[16][16];        // 1 KB

    const int t = threadIdx.x;
    const int lane = t & 63;
    const int w = t >> 6;                 // k-sixteenth 0..15
    const int bx = blockIdx.x;
    const int itile = bx >> 1;
    const int bh = bx & 1;
    const int i0 = itile * 16;

    const int rl = lane & 15;
    const int kbase = w * 128 + ((lane >> 4) << 3);

    // ---- prefetch theta-update inputs (waves 0..1) ----
    float th_o = 0.0f, sin_i = 0.0f, cos_i = 0.0f, om_i = 0.0f;
    size_t o_upd = 0;
    if (t < 128) {
        const int bs = t >> 4;            // 0..7
        const int il = t & 15;
        const int b2 = bh * 8 + bs;
        o_upd = (size_t)b2 * NOSC + i0 + il;
        om_i = omega[i0 + il];
        if constexpr (MODE == 0) {
            th_o = theta_in[o_upd];
            sincosf(th_o, &sin_i, &cos_i);
        } else {
            th_o = th[o_upd];
            sin_i = bf2f(Rc[o_upd]);
            cos_i = bf2f(Rc[M_TOT + o_upd]);
        }
    }
    const float scale = kg[0] * (1.0f + mod[0]) * (1.0f / (float)NOSC);

    bf16x8 afr[4], bfr[4];

    if constexpr (MODE == 0) {
        __shared__ unsigned short Kt[16][KTP];      // 64.25 KB (step 0 only)
        const float4* __restrict__ src =
            reinterpret_cast<const float4*>(Kmat + (size_t)i0 * NOSC);
#pragma unroll
        for (int p = 0; p < 8; ++p) {
            const int q = t + p * 1024;             // float4 index 0..8191
            float4 v = src[q];
            ushort4 u = {f2bf(v.x), f2bf(v.y), f2bf(v.z), f2bf(v.w)};
            const int row = q >> 9;
            const int col = (q & 511) * 4;
            *reinterpret_cast<ushort4*>(&Kt[row][col]) = u;
            if (bh == 0)
                *reinterpret_cast<ushort4*>(Kb + (size_t)(i0 + row) * NOSC + col) = u;
        }
        if (bx == 0 && t == 0) {                    // zero coherence accumulators
            for (int q = 0; q < 32; ++q) accum[q] = 0.0f;
            *ticket = 0;
        }
        __syncthreads();
#pragma unroll
        for (int it2 = 0; it2 < 4; ++it2)
            bfr[it2] = *reinterpret_cast<const bf16x8*>(&Kt[rl][kbase + it2 * 32]);
        // A fragments from sincos of theta_in (rows: rl<8 sin, rl>=8 cos)
        const int ab = bh * 8 + (rl & 7);
        const float* __restrict__ tp = theta_in + (size_t)ab * NOSC + kbase;
#pragma unroll
        for (int it2 = 0; it2 < 4; ++it2) {
            bf16x8 a;
#pragma unroll
            for (int e = 0; e < 8; ++e) {
                float s, c;
                sincosf(tp[it2 * 32 + e], &s, &c);
                a[e] = (short)((rl < 8) ? f2bf(s) : f2bf(c));
            }
            afr[it2] = a;
        }
    } else {
        const unsigned short* __restrict__ pb =
            Kb + (size_t)(i0 + rl) * NOSC + kbase;
        const int arow = (rl < 8) ? (bh * 8 + rl) : (16 + bh * 8 + (rl - 8));
        const unsigned short* __restrict__ pa =
            Rc + (size_t)arow * NOSC + kbase;
#pragma unroll
        for (int it2 = 0; it2 < 4; ++it2) {
            bfr[it2] = *reinterpret_cast<const bf16x8*>(pb + it2 * 32);
            afr[it2] = *reinterpret_cast<const bf16x8*>(pa + it2 * 32);
        }
    }

    f32x4 acc = {0.0f, 0.0f, 0.0f, 0.0f};
#pragma unroll
    for (int it2 = 0; it2 < 4; ++it2)
        acc = __builtin_amdgcn_mfma_f32_16x16x32_bf16(afr[it2], bfr[it2], acc, 0, 0, 0);

    *reinterpret_cast<f32x4*>(&part[w][lane][0]) = acc;
    __syncthreads();

    // reduce 16 k-partials: D row r=(ln>>4)*4+rg, col il
    if (t < 256) {
        const int r = t >> 4;            // 0..15
        const int il = t & 15;
        const int ln = ((r >> 2) << 4) | il;
        const int rg = r & 3;
        float s = 0.0f;
#pragma unroll
        for (int q = 0; q < 16; ++q) s += part[q][ln][rg];
        coup[r][il] = s;
    }
    __syncthreads();

    // theta update for this block's 128 (b, i)
    if (t < 128) {
        const int bs = t >> 4;
        const int il = t & 15;
        const float aS = coup[bs][il];        // sin-dot rows 0..7
        const float aC = coup[8 + bs][il];    // cos-dot rows 8..15
        float nt = th_o + DT * (om_i + scale * (cos_i * aS - sin_i * aC));
        float ws, wc;
        sincosf(nt, &ws, &wc);
        if constexpr (MODE == 2) {
            th[o_upd] = atan2f(ws, wc);       // final wrap
            // coherence partial: reduce over il (16-lane groups)
#pragma unroll
            for (int m = 1; m < 16; m <<= 1) {
                ws += __shfl_xor(ws, m);
                wc += __shfl_xor(wc, m);
            }
            if (il == 0) {
                const int b2 = bh * 8 + bs;
                atomicAdd(&accum[b2], ws);
                atomicAdd(&accum[16 + b2], wc);
            }
        } else {
            // wrap only shifts theta by 2*pi*k -> sin/cos unchanged; defer atan2
            th[o_upd] = nt;
            Rn[o_upd] = f2bf(ws);
            Rn[M_TOT + o_upd] = f2bf(wc);
        }
    }

    if constexpr (MODE == 2) {
        __threadfence();
        __syncthreads();
        if (t == 0) {
            const int tk = atomicAdd(ticket, 1);
            if (tk == 255) {                  // last block finalizes
                for (int b2 = 0; b2 < NB; ++b2) {
                    float ss = atomicAdd(&accum[b2], 0.0f) * (1.0f / (float)NOSC);
                    float sc = atomicAdd(&accum[16 + b2], 0.0f) * (1.0f / (float)NOSC);
                    coh[b2] = sqrtf(ss * ss + sc * sc);
                }
            }
        }
    }
}

extern "C" void kernel_launch(void* const* d_in, const int* in_sizes, int n_in,
                              void* d_out, int out_size, void* d_ws, size_t ws_size,
                              hipStream_t stream) {
    const float* theta_in = (const float*)d_in[0];
    const float* Kmat     = (const float*)d_in[1];
    const float* omega    = (const float*)d_in[2];
    const float* kg       = (const float*)d_in[3];
    const float* mod      = (const float*)d_in[4];

    float* th  = (float*)d_out;               // [NB][NOSC] final theta
    float* coh = (float*)d_out + M_TOT;       // [NB]

    unsigned short* Kb = (unsigned short*)d_ws;                       // 8 MB
    unsigned short* RA = (unsigned short*)d_ws + (size_t)NOSC * NOSC; // 128 KB
    unsigned short* RB = RA + 2 * M_TOT;                              // 128 KB
    float* accum = (float*)(RB + 2 * M_TOT);                          // 32 f32
    int* ticket = (int*)(accum + 32);

    // step 0: K convert + init from theta_in, writes RA
    step_kernel<0><<<256, 1024, 0, stream>>>(
        theta_in, Kmat, Kb, RA, RA, omega, kg, mod, th, coh, accum, ticket);

    // steps 1..8: s odd reads RA writes RB; s even reads RB writes RA
    for (int s = 1; s < 9; ++s) {
        const unsigned short* rc = (s & 1) ? RA : RB;
        unsigned short* rn = (s & 1) ? RB : RA;
        step_kernel<1><<<256, 1024, 0, stream>>>(
            theta_in, Kmat, Kb, rc, rn, omega, kg, mod, th, coh, accum, ticket);
    }

    // step 9 (s=9 odd -> reads RA): wrap + fused coherence
    step_kernel<2><<<256, 1024, 0, stream>>>(
        theta_in, Kmat, Kb, RA, RB, omega, kg, mod, th, coh, accum, ticket);
}